// Round 1
// baseline (248.121 us; speedup 1.0000x reference)
//
#include <hip/hip_runtime.h>
#include <math.h>

// Problem constants (B,N,D)=(8,2048,256), S=128, H=512, E=2H+S=1152
#define BB 8
#define NN 2048
#define DD 256
#define SS 128
#define HH 512
#define EE 1152

typedef short bf16x8 __attribute__((ext_vector_type(8)));
typedef float f32x4 __attribute__((ext_vector_type(4)));

__device__ __forceinline__ short f2bf(float f) {
    union { float f; unsigned u; } a; a.f = f;
    unsigned r = a.u + 0x7FFFu + ((a.u >> 16) & 1u);  // RNE
    return (short)(r >> 16);
}
__device__ __forceinline__ float bf2f(short s) {
    union { unsigned u; float f; } a; a.u = ((unsigned)(unsigned short)s) << 16;
    return a.f;
}

// ---------------- K1: RMS norm, x fp32 -> xn bf16 --------------------------
// 4 waves/block, one row (D=256) per wave, float4 loads + shuffle reduce.
__global__ __launch_bounds__(256) void k_rmsnorm(
        const float* __restrict__ x, const float* __restrict__ gp,
        short* __restrict__ xn) {
    int wave = threadIdx.x >> 6, lane = threadIdx.x & 63;
    long row = (long)blockIdx.x * 4 + wave;
    float4 xv = ((const float4*)(x + row * DD))[lane];
    float ss = xv.x*xv.x + xv.y*xv.y + xv.z*xv.z + xv.w*xv.w;
    #pragma unroll
    for (int off = 32; off > 0; off >>= 1) ss += __shfl_down(ss, off);
    ss = __shfl(ss, 0);
    float norm = sqrtf(ss) * 0.0625f;              // ||x|| / sqrt(256)
    float scale = gp[0] / fmaxf(norm, 1e-5f);
    short4 o;
    o.x = f2bf(xv.x * scale); o.y = f2bf(xv.y * scale);
    o.z = f2bf(xv.z * scale); o.w = f2bf(xv.w * scale);
    ((short4*)(xn + row * DD))[lane] = o;
}

// ---------------- K2: weight prep (transpose + bf16 cast) ------------------
// Wuv (D x E) -> Wuv_t (E x D) bf16 ; Wo (H x D) -> Wo_t (D x H) bf16
__global__ void k_prep(const float* __restrict__ Wuv, const float* __restrict__ Wo,
                       short* __restrict__ Wuv_t, short* __restrict__ Wo_t) {
    int idx = blockIdx.x * 256 + threadIdx.x;
    if (idx < DD * EE) {
        int d = idx / EE, e = idx % EE;
        Wuv_t[e * DD + d] = f2bf(Wuv[idx]);
    }
    int i2 = idx - DD * EE;
    if (i2 >= 0 && i2 < HH * DD) {
        int h = i2 / DD, d = i2 % DD;
        Wo_t[d * HH + h] = f2bf(Wo[i2]);
    }
}

// ---------------- K3: GEMM1 + silu + split epilogue ------------------------
// (16384 x 256) @ (256 x 1152), 64x64 tile/block, 4 waves, 16x16x32 MFMA.
__global__ __launch_bounds__(256) void k_gemm1(
        const short* __restrict__ xn, const short* __restrict__ Wuv_t,
        const float* __restrict__ b_uv,
        const float* __restrict__ gamma, const float* __restrict__ beta,
        short* __restrict__ u, short* __restrict__ v,
        short* __restrict__ q, short* __restrict__ k) {
    __shared__ short As[64][72];   // +8 pad: rotate banks by 4/row
    __shared__ short Bs[64][72];
    int m0 = blockIdx.x * 64, n0 = blockIdx.y * 64;
    int t = threadIdx.x, w = t >> 6, lane = t & 63;
    int wr = w & 1, wc = w >> 1, l16 = lane & 15, quad = lane >> 4;
    int srow = t >> 3, sch = (t & 7) * 8;
    f32x4 acc[2][2] = {};
    for (int k0 = 0; k0 < DD; k0 += 64) {
        __syncthreads();
        *(bf16x8*)&As[srow][sch]    = *(const bf16x8*)&xn[(long)(m0+srow)*DD + k0 + sch];
        *(bf16x8*)&As[srow+32][sch] = *(const bf16x8*)&xn[(long)(m0+srow+32)*DD + k0 + sch];
        *(bf16x8*)&Bs[srow][sch]    = *(const bf16x8*)&Wuv_t[(long)(n0+srow)*DD + k0 + sch];
        *(bf16x8*)&Bs[srow+32][sch] = *(const bf16x8*)&Wuv_t[(long)(n0+srow+32)*DD + k0 + sch];
        __syncthreads();
        #pragma unroll
        for (int kk = 0; kk < 2; kk++) {
            bf16x8 a0 = *(const bf16x8*)&As[wr*32 +      l16][kk*32 + quad*8];
            bf16x8 a1 = *(const bf16x8*)&As[wr*32 + 16 + l16][kk*32 + quad*8];
            bf16x8 b0 = *(const bf16x8*)&Bs[wc*32 +      l16][kk*32 + quad*8];
            bf16x8 b1 = *(const bf16x8*)&Bs[wc*32 + 16 + l16][kk*32 + quad*8];
            acc[0][0] = __builtin_amdgcn_mfma_f32_16x16x32_bf16(a0, b0, acc[0][0], 0,0,0);
            acc[0][1] = __builtin_amdgcn_mfma_f32_16x16x32_bf16(a0, b1, acc[0][1], 0,0,0);
            acc[1][0] = __builtin_amdgcn_mfma_f32_16x16x32_bf16(a1, b0, acc[1][0], 0,0,0);
            acc[1][1] = __builtin_amdgcn_mfma_f32_16x16x32_bf16(a1, b1, acc[1][1], 0,0,0);
        }
    }
    #pragma unroll
    for (int mt = 0; mt < 2; mt++)
    #pragma unroll
    for (int nt = 0; nt < 2; nt++)
    #pragma unroll
    for (int r = 0; r < 4; r++) {
        int gm = m0 + wr*32 + mt*16 + quad*4 + r;     // C/D: row=(lane>>4)*4+reg
        int ge = n0 + wc*32 + nt*16 + l16;            //      col=lane&15
        float val = acc[mt][nt][r] + b_uv[ge];
        val = val / (1.0f + __expf(-val));            // silu
        if (ge < HH) {
            u[(long)gm*HH + ge] = f2bf(val);
        } else if (ge < 2*HH) {
            v[(long)gm*HH + (ge - HH)] = f2bf(val);
        } else {
            int si = ge - 2*HH;
            q[(long)gm*SS + si] = f2bf(val * gamma[si]      + beta[si]);
            k[(long)gm*SS + si] = f2bf(val * gamma[SS + si] + beta[SS + si]);
        }
    }
}

// ---------------- K4: transpose v -> v_t per batch -------------------------
__global__ void k_transpose_v(const short* __restrict__ v, short* __restrict__ v_t) {
    __shared__ short tile[32][33];
    int n0 = blockIdx.x * 32, h0 = blockIdx.y * 32, b = blockIdx.z;
    int t = threadIdx.x;
    const short* vb = v + (long)b * NN * HH;
    short* vtb = v_t + (long)b * HH * NN;
    #pragma unroll
    for (int i = 0; i < 4; i++) {
        int idx = t + i * 256, r = idx >> 5, c = idx & 31;
        tile[r][c] = vb[(long)(n0 + r) * HH + h0 + c];
    }
    __syncthreads();
    #pragma unroll
    for (int i = 0; i < 4; i++) {
        int idx = t + i * 256, r = idx >> 5, c = idx & 31;
        vtb[(long)(h0 + r) * NN + n0 + c] = tile[c][r];
    }
}

// ---------------- K5: fused relu^2 attention + u-gate ----------------------
// Block = (batch b, 32 q-rows), streams m in tiles of 32, full H=512 in regs.
// blockIdx&7 = batch -> batch pinned to one XCD (k/v/q ~3MB fits 4MB L2).
__global__ __launch_bounds__(256) void k_attn(
        const short* __restrict__ q, const short* __restrict__ k,
        const short* __restrict__ v_t, const short* __restrict__ u,
        short* __restrict__ gated) {
    __shared__ short qs[32][136];
    __shared__ short ks[32][136];
    __shared__ short vts[512][40];
    __shared__ short Ps[32][40];
    int b = blockIdx.x & 7;
    int i0 = (blockIdx.x >> 3) * 32;
    int t = threadIdx.x, w = t >> 6, lane = t & 63;
    int l16 = lane & 15, quad = lane >> 4;
    int rh = w & 1, cq = w >> 1;   // PV: row half, col half (256 cols each)
    const short* qb  = q   + ((long)b * NN + i0) * SS;
    const short* kb  = k   + (long)b * NN * SS;
    const short* vtb = v_t + (long)b * HH * NN;
    #pragma unroll
    for (int i = 0; i < 2; i++) {   // stage q tile once
        int idx = t + i * 256, row = idx >> 4, ch = (idx & 15) * 8;
        *(bf16x8*)&qs[row][ch] = *(const bf16x8*)&qb[(long)row * SS + ch];
    }
    f32x4 acc[16] = {};
    for (int m0 = 0; m0 < NN; m0 += 32) {
        __syncthreads();   // prev PV done with ks/vts/Ps (iter0: q staged)
        #pragma unroll
        for (int i = 0; i < 2; i++) {
            int idx = t + i * 256, row = idx >> 4, ch = (idx & 15) * 8;
            *(bf16x8*)&ks[row][ch] = *(const bf16x8*)&kb[(long)(m0 + row) * SS + ch];
        }
        #pragma unroll
        for (int i = 0; i < 8; i++) {
            int idx = t + i * 256, hr = idx >> 2, ch = (idx & 3) * 8;
            *(bf16x8*)&vts[hr][ch] = *(const bf16x8*)&vtb[(long)hr * NN + m0 + ch];
        }
        __syncthreads();
        // QK: wave w computes 16x16 score tile (rows (w&1)*16, cols (w>>1)*16)
        f32x4 sc = {};
        #pragma unroll
        for (int kk = 0; kk < 4; kk++) {
            bf16x8 aq = *(const bf16x8*)&qs[(w&1)*16  + l16][kk*32 + quad*8];
            bf16x8 bk = *(const bf16x8*)&ks[(w>>1)*16 + l16][kk*32 + quad*8];
            sc = __builtin_amdgcn_mfma_f32_16x16x32_bf16(aq, bk, sc, 0,0,0);
        }
        #pragma unroll
        for (int r = 0; r < 4; r++) {
            float s = fmaxf(sc[r] * 0.08838834764831845f, 0.0f);  // 1/sqrt(128)
            Ps[(w&1)*16 + quad*4 + r][(w>>1)*16 + l16] = f2bf(s * s);
        }
        __syncthreads();
        // PV: A = Ps row-half (reused over 16 col tiles), B = v_t rows
        bf16x8 ap = *(const bf16x8*)&Ps[rh*16 + l16][quad*8];
        #pragma unroll
        for (int j = 0; j < 16; j++) {
            int ct = cq * 16 + j;
            bf16x8 bv = *(const bf16x8*)&vts[ct*16 + l16][quad*8];
            acc[j] = __builtin_amdgcn_mfma_f32_16x16x32_bf16(ap, bv, acc[j], 0,0,0);
        }
    }
    long rowbase = (long)b * NN + i0;
    #pragma unroll
    for (int j = 0; j < 16; j++) {
        int gh = (cq * 16 + j) * 16 + l16;
        #pragma unroll
        for (int r = 0; r < 4; r++) {
            long grow = rowbase + rh*16 + quad*4 + r;
            float uval = bf2f(u[grow * HH + gh]);
            gated[grow * HH + gh] = f2bf(acc[j][r] * uval);
        }
    }
}

// ---------------- K6: GEMM2 + bias -> fp32 out -----------------------------
__global__ __launch_bounds__(256) void k_gemm2(
        const short* __restrict__ gated, const short* __restrict__ Wo_t,
        const float* __restrict__ b_o, float* __restrict__ out) {
    __shared__ short As[64][72];
    __shared__ short Bs[64][72];
    int m0 = blockIdx.x * 64, n0 = blockIdx.y * 64;
    int t = threadIdx.x, w = t >> 6, lane = t & 63;
    int wr = w & 1, wc = w >> 1, l16 = lane & 15, quad = lane >> 4;
    int srow = t >> 3, sch = (t & 7) * 8;
    f32x4 acc[2][2] = {};
    for (int k0 = 0; k0 < HH; k0 += 64) {
        __syncthreads();
        *(bf16x8*)&As[srow][sch]    = *(const bf16x8*)&gated[(long)(m0+srow)*HH + k0 + sch];
        *(bf16x8*)&As[srow+32][sch] = *(const bf16x8*)&gated[(long)(m0+srow+32)*HH + k0 + sch];
        *(bf16x8*)&Bs[srow][sch]    = *(const bf16x8*)&Wo_t[(long)(n0+srow)*HH + k0 + sch];
        *(bf16x8*)&Bs[srow+32][sch] = *(const bf16x8*)&Wo_t[(long)(n0+srow+32)*HH + k0 + sch];
        __syncthreads();
        #pragma unroll
        for (int kk = 0; kk < 2; kk++) {
            bf16x8 a0 = *(const bf16x8*)&As[wr*32 +      l16][kk*32 + quad*8];
            bf16x8 a1 = *(const bf16x8*)&As[wr*32 + 16 + l16][kk*32 + quad*8];
            bf16x8 b0 = *(const bf16x8*)&Bs[wc*32 +      l16][kk*32 + quad*8];
            bf16x8 b1 = *(const bf16x8*)&Bs[wc*32 + 16 + l16][kk*32 + quad*8];
            acc[0][0] = __builtin_amdgcn_mfma_f32_16x16x32_bf16(a0, b0, acc[0][0], 0,0,0);
            acc[0][1] = __builtin_amdgcn_mfma_f32_16x16x32_bf16(a0, b1, acc[0][1], 0,0,0);
            acc[1][0] = __builtin_amdgcn_mfma_f32_16x16x32_bf16(a1, b0, acc[1][0], 0,0,0);
            acc[1][1] = __builtin_amdgcn_mfma_f32_16x16x32_bf16(a1, b1, acc[1][1], 0,0,0);
        }
    }
    #pragma unroll
    for (int mt = 0; mt < 2; mt++)
    #pragma unroll
    for (int nt = 0; nt < 2; nt++)
    #pragma unroll
    for (int r = 0; r < 4; r++) {
        int gm = m0 + wr*32 + mt*16 + quad*4 + r;
        int gd = n0 + wc*32 + nt*16 + l16;
        out[(long)gm*DD + gd] = acc[mt][nt][r] + b_o[gd];
    }
}

extern "C" void kernel_launch(void* const* d_in, const int* in_sizes, int n_in,
                              void* d_out, int out_size, void* d_ws, size_t ws_size,
                              hipStream_t stream) {
    const float* x     = (const float*)d_in[0];
    const float* g     = (const float*)d_in[1];
    const float* Wuv   = (const float*)d_in[2];
    const float* b_uv  = (const float*)d_in[3];
    const float* gamma = (const float*)d_in[4];
    const float* beta  = (const float*)d_in[5];
    const float* Wo    = (const float*)d_in[6];
    const float* b_o   = (const float*)d_in[7];
    float* out = (float*)d_out;

    // workspace layout (bf16/short elements), ~84.7 MB total
    short* ws    = (short*)d_ws;
    short* xn    = ws;                                  // 16384*256
    short* Wuv_t = xn    + (long)16384 * 256;           // 1152*256
    short* Wo_t  = Wuv_t + (long)1152 * 256;            // 256*512
    short* u     = Wo_t  + (long)256 * 512;             // 16384*512
    short* v     = u     + (long)16384 * 512;           // 16384*512
    short* v_t   = v     + (long)16384 * 512;           // 16384*512
    short* qq    = v_t   + (long)16384 * 512;           // 16384*128
    short* kk    = qq    + (long)16384 * 128;           // 16384*128
    short* gated = kk    + (long)16384 * 128;           // 16384*512

    k_rmsnorm<<<4096, 256, 0, stream>>>(x, g, xn);
    k_prep<<<(DD*EE + HH*DD + 255) / 256, 256, 0, stream>>>(Wuv, Wo, Wuv_t, Wo_t);
    k_gemm1<<<dim3(256, 18), 256, 0, stream>>>(xn, Wuv_t, b_uv, gamma, beta, u, v, qq, kk);
    k_transpose_v<<<dim3(64, 16, 8), 256, 0, stream>>>(v, v_t);
    k_attn<<<512, 256, 0, stream>>>(qq, kk, v_t, u, gated);
    k_gemm2<<<dim3(256, 4), 256, 0, stream>>>(gated, Wo_t, b_o, out);
}